// Round 1
// baseline (12159.459 us; speedup 1.0000x reference)
//
#include <hip/hip_runtime.h>

#define TT 200
#define BB 128
#define CC 171
#define HH 1024
#define XPAD 192
#define FOURH 4096

typedef __attribute__((ext_vector_type(8))) short short8;
typedef __attribute__((ext_vector_type(4))) float f32x4;

__device__ __forceinline__ unsigned short f2bf(float f) {
  unsigned int u = __float_as_uint(f);
  u += 0x7fff + ((u >> 16) & 1);   // RNE
  return (unsigned short)(u >> 16);
}
__device__ __forceinline__ float sigmoidf_(float x) { return 1.f / (1.f + __expf(-x)); }

__device__ __forceinline__ void gload_lds16(const void* g, void* l) {
  __builtin_amdgcn_global_load_lds(
      (const __attribute__((address_space(1))) void*)g,
      (__attribute__((address_space(3))) void*)l, 16, 0, 0);
}

// ---------------- fused GEMM + LSTM cell update ----------------
// gates[128 x 4096] = [A1|A2] @ W^T + bias   (W gate-permuted, row-major [4096][sW])
// WG tile: M32 x N64 (= 16 units x 4 gates under permutation). 4 waves, wave w = gate w.
__global__ __launch_bounds__(256, 1) void lstm_gemm(
    const unsigned short* __restrict__ A1, int sA1, int nkt1,
    const unsigned short* __restrict__ A2, int sA2,
    const unsigned short* __restrict__ W, int sW, int nkt,
    const float* __restrict__ bias,
    float* __restrict__ Cst,
    unsigned short* __restrict__ Hout)
{
  __shared__ char smem[24576];   // 2 x (A 4KB + B 8KB)
  const int tid = threadIdx.x;
  const int wave = tid >> 6, lane = tid & 63;
  const int lrow = lane >> 3, lj = lane & 7;
  const int fl = lane & 15, fh = lane >> 4;
  const int m0 = blockIdx.y * 32;
  const int n0 = blockIdx.x * 64;

  f32x4 acc0 = {0.f, 0.f, 0.f, 0.f}, acc1 = {0.f, 0.f, 0.f, 0.f};

  auto stage = [&](int kt, int buf) {
    char* base = smem + buf * 12288;
    { // A tile 32x64
      int row = wave * 8 + lrow;
      const unsigned short* src; int col;
      if (kt < nkt1) { src = A1 + (size_t)(m0 + row) * sA1; col = kt * 64; }
      else           { src = A2 + (size_t)(m0 + row) * sA2; col = (kt - nkt1) * 64; }
      const unsigned short* g = src + col + ((lj ^ (row & 7)) << 3);
      gload_lds16(g, base + wave * 1024);
    }
    int k0 = kt * 64;
    for (int i = 0; i < 2; ++i) { // B tile 64x64
      int row = i * 32 + wave * 8 + lrow;
      const unsigned short* g = W + (size_t)(n0 + row) * sW + k0 + ((lj ^ (row & 7)) << 3);
      gload_lds16(g, base + 4096 + (i * 32 + wave * 8) * 128);
    }
  };

  stage(0, 0);
  __syncthreads();
  for (int kt = 0; kt < nkt; ++kt) {
    int cur = kt & 1;
    if (kt + 1 < nkt) stage(kt + 1, cur ^ 1);
    char* Ab = smem + cur * 12288;
    char* Bb = Ab + 4096;
#pragma unroll
    for (int kk = 0; kk < 2; ++kk) {
      int colb = kk * 64 + fh * 16;
      int ar0 = fl, ar1 = 16 + fl;
      short8 a0 = *(const short8*)(Ab + ar0 * 128 + (colb ^ ((ar0 & 7) << 4)));
      short8 a1 = *(const short8*)(Ab + ar1 * 128 + (colb ^ ((ar1 & 7) << 4)));
      int br = wave * 16 + fl;
      short8 b0 = *(const short8*)(Bb + br * 128 + (colb ^ ((br & 7) << 4)));
      acc0 = __builtin_amdgcn_mfma_f32_16x16x32_bf16(a0, b0, acc0, 0, 0, 0);
      acc1 = __builtin_amdgcn_mfma_f32_16x16x32_bf16(a1, b0, acc1, 0, 0, 0);
    }
    __syncthreads();
  }

  // gate exchange: ex[gate][row 0..31][unit 0..15] fp32
  float* ex = (float*)smem;
  float bval = bias[n0 + wave * 16 + fl];
#pragma unroll
  for (int r = 0; r < 4; ++r) {
    ex[(wave * 32 + (fh * 4 + r)) * 16 + fl] = acc0[r] + bval;
    ex[(wave * 32 + 16 + (fh * 4 + r)) * 16 + fl] = acc1[r] + bval;
  }
  __syncthreads();
  for (int idx = tid; idx < 512; idx += 256) {
    int row = idx >> 4, uu = idx & 15;
    float gi = ex[(0 * 32 + row) * 16 + uu];
    float gf = ex[(1 * 32 + row) * 16 + uu];
    float gg = ex[(2 * 32 + row) * 16 + uu];
    float go = ex[(3 * 32 + row) * 16 + uu];
    int batch = m0 + row;
    int unit = blockIdx.x * 16 + uu;
    size_t ci = (size_t)batch * HH + unit;
    float c = Cst[ci];
    float cn = sigmoidf_(gf) * c + sigmoidf_(gi) * tanhf(gg);
    Cst[ci] = cn;
    Hout[ci] = f2bf(sigmoidf_(go) * tanhf(cn));
  }
}

// ---------------- decoder GEMM + next-x preparation ----------------
__global__ __launch_bounds__(256, 1) void dec_gemm(
    const unsigned short* __restrict__ H3,
    const unsigned short* __restrict__ Wd,   // [176][1024] bf16, rows>=171 zero
    const float* __restrict__ bd,
    float* __restrict__ out,
    const float* __restrict__ seq,
    unsigned short* __restrict__ X,
    const int* __restrict__ gtp, const int* __restrict__ condp,
    int t)
{
  __shared__ char smem[36864];  // 2 x (A 16KB + B 2KB)
  const int tid = threadIdx.x;
  const int wave = tid >> 6, lane = tid & 63;
  const int lrow = lane >> 3, lj = lane & 7;
  const int fl = lane & 15, fh = lane >> 4;
  const int n0 = blockIdx.x * 16;
  f32x4 acc0 = {0.f, 0.f, 0.f, 0.f}, acc1 = {0.f, 0.f, 0.f, 0.f};

  auto stage = [&](int kt, int buf) {
    char* base = smem + buf * 18432;
    int k0 = kt * 64;
#pragma unroll
    for (int i = 0; i < 4; ++i) { // A: 128x64
      int row = i * 32 + wave * 8 + lrow;
      const unsigned short* g = H3 + (size_t)row * HH + k0 + ((lj ^ (row & 7)) << 3);
      gload_lds16(g, base + (i * 32 + wave * 8) * 128);
    }
    if (wave < 2) { // B: 16x64
      int row = wave * 8 + lrow;
      const unsigned short* g = Wd + (size_t)(n0 + row) * HH + k0 + ((lj ^ (row & 7)) << 3);
      gload_lds16(g, base + 16384 + (wave * 8) * 128);
    }
  };

  stage(0, 0);
  __syncthreads();
  const int nkt = 16;
  for (int kt = 0; kt < nkt; ++kt) {
    int cur = kt & 1;
    if (kt + 1 < nkt) stage(kt + 1, cur ^ 1);
    char* Ab = smem + cur * 18432;
    char* Bb = Ab + 16384;
#pragma unroll
    for (int kk = 0; kk < 2; ++kk) {
      int colb = kk * 64 + fh * 16;
      int ar0 = wave * 32 + fl, ar1 = wave * 32 + 16 + fl;
      short8 a0 = *(const short8*)(Ab + ar0 * 128 + (colb ^ ((ar0 & 7) << 4)));
      short8 a1 = *(const short8*)(Ab + ar1 * 128 + (colb ^ ((ar1 & 7) << 4)));
      int br = fl;
      short8 b0 = *(const short8*)(Bb + br * 128 + (colb ^ ((br & 7) << 4)));
      acc0 = __builtin_amdgcn_mfma_f32_16x16x32_bf16(a0, b0, acc0, 0, 0, 0);
      acc1 = __builtin_amdgcn_mfma_f32_16x16x32_bf16(a1, b0, acc1, 0, 0, 0);
    }
    __syncthreads();
  }

  int c = n0 + fl;
  if (c < CC) {
    float bv = bd[c];
    bool havenext = (t + 1) < TT;
    int per = *gtp + *condp;
    bool ug = false;
    if (havenext) ug = (per > 0) ? (((t + 1) % per) < *gtp) : false;
#pragma unroll
    for (int mi = 0; mi < 2; ++mi) {
      f32x4 acc = mi ? acc1 : acc0;
#pragma unroll
      for (int r = 0; r < 4; ++r) {
        int batch = wave * 32 + mi * 16 + fh * 4 + r;
        float val = acc[r] + bv;
        out[(size_t)batch * TT * CC + (size_t)t * CC + c] = val;
        if (havenext) {
          float xv = ug ? seq[(size_t)batch * TT * CC + (size_t)(t + 1) * CC + c] : val;
          X[batch * XPAD + c] = f2bf(xv);
        }
      }
    }
  }
}

// ---------------- conversion / init kernels ----------------
__device__ __forceinline__ int perm_orig_row(int np) {
  return ((np >> 4) & 3) * HH + ((np >> 6) << 4) + (np & 15);
}

__global__ void conv_w1(const float* __restrict__ Wih, const float* __restrict__ Whh,
                        unsigned short* __restrict__ dst) {
  int k = blockIdx.x * 256 + threadIdx.x;
  int np = blockIdx.y;
  if (k >= 1216) return;
  int n = perm_orig_row(np);
  float v;
  if (k < XPAD) v = (k < CC) ? Wih[(size_t)n * CC + k] : 0.f;
  else          v = Whh[(size_t)n * HH + (k - XPAD)];
  dst[(size_t)np * 1216 + k] = f2bf(v);
}

__global__ void conv_w23(const float* __restrict__ Wih, const float* __restrict__ Whh,
                         unsigned short* __restrict__ dst) {
  int k = blockIdx.x * 256 + threadIdx.x; // 0..2047
  int np = blockIdx.y;
  int n = perm_orig_row(np);
  float v = (k < HH) ? Wih[(size_t)n * HH + k] : Whh[(size_t)n * HH + (k - HH)];
  dst[(size_t)np * 2048 + k] = f2bf(v);
}

__global__ void conv_wd(const float* __restrict__ Wsrc, unsigned short* __restrict__ dst) {
  int k = blockIdx.x * 256 + threadIdx.x; // 0..1023
  int row = blockIdx.y;                   // 0..175
  float v = (row < CC) ? Wsrc[(size_t)row * HH + k] : 0.f;
  dst[(size_t)row * HH + k] = f2bf(v);
}

__global__ void conv_bias(const float* bi1, const float* bh1, const float* bi2, const float* bh2,
                          const float* bi3, const float* bh3, const float* bdec,
                          float* o1, float* o2, float* o3, float* od) {
  int idx = blockIdx.x * 256 + threadIdx.x;
  if (idx < 3 * FOURH) {
    int l = idx >> 12; int np = idx & 4095;
    int n = perm_orig_row(np);
    const float* bi = (l == 0) ? bi1 : ((l == 1) ? bi2 : bi3);
    const float* bh = (l == 0) ? bh1 : ((l == 1) ? bh2 : bh3);
    float* o = (l == 0) ? o1 : ((l == 1) ? o2 : o3);
    o[np] = bi[n] + bh[n];
  } else {
    int c2 = idx - 3 * FOURH;
    if (c2 < 176) od[c2] = (c2 < CC) ? bdec[c2] : 0.f;
  }
}

__global__ void init_state(unsigned short* __restrict__ Hall, float* __restrict__ Call,
                           unsigned short* __restrict__ X, const float* __restrict__ seq,
                           const int* __restrict__ gtp) {
  int idx = blockIdx.x * blockDim.x + threadIdx.x;
  if (idx < 3 * 2 * BB * HH) Hall[idx] = 0;
  if (idx < 3 * BB * HH) Call[idx] = 0.f;
  if (idx < BB * XPAD) {
    int b = idx / XPAD, cc = idx % XPAD;
    float v = 0.f;
    if (cc < CC && (*gtp) > 0) v = seq[(size_t)b * TT * CC + cc];
    X[idx] = f2bf(v);
  }
}

extern "C" void kernel_launch(void* const* d_in, const int* in_sizes, int n_in,
                              void* d_out, int out_size, void* d_ws, size_t ws_size,
                              hipStream_t stream)
{
  const float* seq   = (const float*)d_in[0];
  const float* W_ih1 = (const float*)d_in[1];
  const float* W_hh1 = (const float*)d_in[2];
  const float* b_ih1 = (const float*)d_in[3];
  const float* b_hh1 = (const float*)d_in[4];
  const float* W_ih2 = (const float*)d_in[5];
  const float* W_hh2 = (const float*)d_in[6];
  const float* b_ih2 = (const float*)d_in[7];
  const float* b_hh2 = (const float*)d_in[8];
  const float* W_ih3 = (const float*)d_in[9];
  const float* W_hh3 = (const float*)d_in[10];
  const float* b_ih3 = (const float*)d_in[11];
  const float* b_hh3 = (const float*)d_in[12];
  const float* W_dec = (const float*)d_in[13];
  const float* b_dec = (const float*)d_in[14];
  const int* condp   = (const int*)d_in[15];
  const int* gtp     = (const int*)d_in[16];
  float* out = (float*)d_out;
  char* ws = (char*)d_ws;

  if (ws_size < 47268864) return;  // need ~45.1 MB scratch

  unsigned short* W1 = (unsigned short*)(ws + 0);
  unsigned short* W2 = (unsigned short*)(ws + 9961472);
  unsigned short* W3 = (unsigned short*)(ws + 26738688);
  unsigned short* Wd = (unsigned short*)(ws + 43515904);
  float* B1 = (float*)(ws + 43876352);
  float* B2 = (float*)(ws + 43941888);
  float* B3 = (float*)(ws + 44007424);
  float* Bd = (float*)(ws + 44072960);
  unsigned short* Hbase = (unsigned short*)(ws + 44073984);
  float* Cbase = (float*)(ws + 45646848);
  unsigned short* X = (unsigned short*)(ws + 47219712);

  unsigned short* H1[2] = { Hbase + 0,            Hbase + 1 * BB * HH };
  unsigned short* H2[2] = { Hbase + 2 * BB * HH,  Hbase + 3 * BB * HH };
  unsigned short* H3[2] = { Hbase + 4 * BB * HH,  Hbase + 5 * BB * HH };
  float* C1 = Cbase;
  float* C2 = Cbase + BB * HH;
  float* C3 = Cbase + 2 * BB * HH;

  conv_w1 <<<dim3(5, 4096), 256, 0, stream>>>(W_ih1, W_hh1, W1);
  conv_w23<<<dim3(8, 4096), 256, 0, stream>>>(W_ih2, W_hh2, W2);
  conv_w23<<<dim3(8, 4096), 256, 0, stream>>>(W_ih3, W_hh3, W3);
  conv_wd <<<dim3(4, 176),  256, 0, stream>>>(W_dec, Wd);
  conv_bias<<<dim3(49), 256, 0, stream>>>(b_ih1, b_hh1, b_ih2, b_hh2, b_ih3, b_hh3, b_dec,
                                          B1, B2, B3, Bd);
  init_state<<<dim3(3072), 256, 0, stream>>>(Hbase, Cbase, X, seq, gtp);

  for (int t = 0; t < TT; ++t) {
    int p = t & 1;
    lstm_gemm<<<dim3(64, 4), 256, 0, stream>>>(X,        XPAD, 3,  H1[p], HH, W1, 1216, 19, B1, C1, H1[1 - p]);
    lstm_gemm<<<dim3(64, 4), 256, 0, stream>>>(H1[1 - p], HH,  16, H2[p], HH, W2, 2048, 32, B2, C2, H2[1 - p]);
    lstm_gemm<<<dim3(64, 4), 256, 0, stream>>>(H2[1 - p], HH,  16, H3[p], HH, W3, 2048, 32, B3, C3, H3[1 - p]);
    dec_gemm <<<dim3(11),    256, 0, stream>>>(H3[1 - p], Wd, Bd, out, seq, X, gtp, condp, t);
  }
}